// Round 4
// baseline (611.809 us; speedup 1.0000x reference)
//
#include <hip/hip_runtime.h>

// Problem constants (from reference setup_inputs)
constexpr int BB    = 2;
constexpr int NN    = 50000;
constexpr int CC    = 64;     // channels == wave size
constexpr int MM    = 50000;
constexpr int KK    = 16;     // neighbors
constexpr int HH    = 8;      // heads -> C/H = 8 channels per head
constexpr int CMID  = 16;
constexpr int TOTAL = BB * MM;        // 100000 points (even; batch edge at 50000 is even)
constexpr int NPAIRS = TOTAL / 2;     // 50000 pairs of adjacent points

// Native clang vector type: __builtin_nontemporal_* rejects HIP_vector_type.
typedef float f32x4 __attribute__((ext_vector_type(4)));

// v4: persistent grid-stride waves, 2 points per wave-iteration.
// R2/R3 evidence: occupancy stuck at 47% with no static limiter -> CP
// dispatch rate can't refill 25k short blocks (Guideline 11). Cap at 2048
// blocks, grid-stride pairs. Pair (2p, 2p+1): one 128B contiguous idx load
// covers both points (lanes 0-15 = A, 16-31 = B); all 64 gathers + 32 guid
// loads + 2 wnet tiles issue back-to-back (~70 loads in flight); compute A
// while B's data lands. Per-point FMA order unchanged (bitwise-identical).
__global__ __launch_bounds__(256) void pcf_kernel(
    const float* __restrict__ feat,   // [B,N,C]
    const int*   __restrict__ inds,   // [B,M,K]
    const float* __restrict__ guid,   // [B,M,K,H]
    const float* __restrict__ wnet,   // [B,M,K,CMID]
    float*       __restrict__ out)    // [B,M,C*CMID]
{
    const int wib    = threadIdx.x >> 6;                  // wave-in-block 0..3
    const int lane   = threadIdx.x & 63;
    const int wslot  = blockIdx.x * 4 + wib;
    const int nslots = gridDim.x * 4;
    const int h      = lane >> 3;                         // head for this channel

    // Per-wave, per-point wnet tiles: 4 waves x 2 points x 1 KiB = 8 KiB/block.
    // Wave-private -> no barriers.
    __shared__ f32x4 swn[4][2][KK * 4];

    for (int pr = wslot; pr < NPAIRS; pr += nslots) {
        const int pA = pr * 2;                 // global point id = b*MM + m
        const int b  = pA / MM;                // same b for A and B (MM even)

        // ---- Issue ALL independent loads for both points back-to-back ----

        // Indices: rows A and B are 32 contiguous ints (128 B, one txn).
        const int* idxp = inds + (size_t)pA * KK;
        int myidx = idxp[lane & 31];           // lanes 0-15: A, 16-31: B

        // Guidance: 32 independent scalar loads (8 distinct dwords each).
        const float* gdA = guid + (size_t)pA * KK * HH;
        const float* gdB = gdA + KK * HH;
        float gA[KK], gB[KK];
#pragma unroll
        for (int k = 0; k < KK; ++k)
            gA[k] = __builtin_nontemporal_load(&gdA[k * HH + h]);
#pragma unroll
        for (int k = 0; k < KK; ++k)
            gB[k] = __builtin_nontemporal_load(&gdB[k * HH + h]);

        // wnet tiles: 2 KiB contiguous (128 f32x4); each lane loads two.
        const f32x4* wp = (const f32x4*)(wnet + (size_t)pA * KK * CMID);
        swn[wib][0][lane] = __builtin_nontemporal_load(&wp[lane]);
        swn[wib][1][lane] = __builtin_nontemporal_load(&wp[64 + lane]);

        // Gathered feature rows: 32 independent coalesced 256 B loads.
        const float* fbase = feat + (size_t)b * NN * CC;
        float fA[KK], fB[KK];
#pragma unroll
        for (int k = 0; k < KK; ++k) {
            const int id = __shfl(myidx, k);            // readlane k (A)
            fA[k] = fbase[(size_t)id * CC + lane];
        }
#pragma unroll
        for (int k = 0; k < KK; ++k) {
            const int id = __shfl(myidx, 16 + k);       // readlane 16+k (B)
            fB[k] = fbase[(size_t)id * CC + lane];
        }

        // Keep-alive: pin all prefetched values in VGPRs so the register
        // allocator cannot sink the loads back into the compute loops
        // (R2: VGPR=44 proved it does exactly that without this).
#pragma unroll
        for (int k = 0; k < KK; ++k)
            asm volatile("" :: "v"(fA[k]), "v"(fB[k]), "v"(gA[k]), "v"(gB[k]));

        // ---- Compute + store point A (B's loads still landing) ----
        {
            float acc[CMID];
#pragma unroll
            for (int i = 0; i < CMID; ++i) acc[i] = 0.f;
#pragma unroll
            for (int k = 0; k < KK; ++k) {
                const float fg = fA[k] * gA[k];
                const f32x4 w0 = swn[wib][0][k * 4 + 0];
                const f32x4 w1 = swn[wib][0][k * 4 + 1];
                const f32x4 w2 = swn[wib][0][k * 4 + 2];
                const f32x4 w3 = swn[wib][0][k * 4 + 3];
                acc[0]  += fg * w0.x;  acc[1]  += fg * w0.y;
                acc[2]  += fg * w0.z;  acc[3]  += fg * w0.w;
                acc[4]  += fg * w1.x;  acc[5]  += fg * w1.y;
                acc[6]  += fg * w1.z;  acc[7]  += fg * w1.w;
                acc[8]  += fg * w2.x;  acc[9]  += fg * w2.y;
                acc[10] += fg * w2.z;  acc[11] += fg * w2.w;
                acc[12] += fg * w3.x;  acc[13] += fg * w3.y;
                acc[14] += fg * w3.z;  acc[15] += fg * w3.w;
            }
            f32x4* o = (f32x4*)(out + (size_t)pA * (CC * CMID) + (size_t)lane * CMID);
            f32x4 o0 = {acc[0],  acc[1],  acc[2],  acc[3]};
            f32x4 o1 = {acc[4],  acc[5],  acc[6],  acc[7]};
            f32x4 o2 = {acc[8],  acc[9],  acc[10], acc[11]};
            f32x4 o3 = {acc[12], acc[13], acc[14], acc[15]};
            o[0] = o0; o[1] = o1; o[2] = o2; o[3] = o3;
        }

        // ---- Compute + store point B ----
        {
            float acc[CMID];
#pragma unroll
            for (int i = 0; i < CMID; ++i) acc[i] = 0.f;
#pragma unroll
            for (int k = 0; k < KK; ++k) {
                const float fg = fB[k] * gB[k];
                const f32x4 w0 = swn[wib][1][k * 4 + 0];
                const f32x4 w1 = swn[wib][1][k * 4 + 1];
                const f32x4 w2 = swn[wib][1][k * 4 + 2];
                const f32x4 w3 = swn[wib][1][k * 4 + 3];
                acc[0]  += fg * w0.x;  acc[1]  += fg * w0.y;
                acc[2]  += fg * w0.z;  acc[3]  += fg * w0.w;
                acc[4]  += fg * w1.x;  acc[5]  += fg * w1.y;
                acc[6]  += fg * w1.z;  acc[7]  += fg * w1.w;
                acc[8]  += fg * w2.x;  acc[9]  += fg * w2.y;
                acc[10] += fg * w2.z;  acc[11] += fg * w2.w;
                acc[12] += fg * w3.x;  acc[13] += fg * w3.y;
                acc[14] += fg * w3.z;  acc[15] += fg * w3.w;
            }
            f32x4* o = (f32x4*)(out + (size_t)(pA + 1) * (CC * CMID) + (size_t)lane * CMID);
            f32x4 o0 = {acc[0],  acc[1],  acc[2],  acc[3]};
            f32x4 o1 = {acc[4],  acc[5],  acc[6],  acc[7]};
            f32x4 o2 = {acc[8],  acc[9],  acc[10], acc[11]};
            f32x4 o3 = {acc[12], acc[13], acc[14], acc[15]};
            o[0] = o0; o[1] = o1; o[2] = o2; o[3] = o3;
        }
    }
}

extern "C" void kernel_launch(void* const* d_in, const int* in_sizes, int n_in,
                              void* d_out, int out_size, void* d_ws, size_t ws_size,
                              hipStream_t stream) {
    const float* feat = (const float*)d_in[0];   // [B,N,C] fp32
    const int*   inds = (const int*)d_in[1];     // [B,M,K] int
    const float* guid = (const float*)d_in[2];   // [B,M,K,H] fp32
    const float* wnet = (const float*)d_in[3];   // [B,M,K,CMID] fp32
    float*       out  = (float*)d_out;           // [B,M,C*CMID] fp32

    // Persistent grid: 2048 blocks (8/CU target), grid-stride over pairs.
    const int blocks = 2048;
    pcf_kernel<<<blocks, 256, 0, stream>>>(feat, inds, guid, wnet, out);
}

// Round 6
// 579.972 us; speedup vs baseline: 1.0549x; 1.0549x over previous
//
#include <hip/hip_runtime.h>

// Problem constants (from reference setup_inputs)
constexpr int BB    = 2;
constexpr int NN    = 50000;
constexpr int CC    = 64;     // channels == wave size
constexpr int MM    = 50000;
constexpr int KK    = 16;     // neighbors
constexpr int HH    = 8;      // heads -> C/H = 8 channels per head
constexpr int CMID  = 16;
constexpr int TOTAL = BB * MM;        // 100000 points

// Native clang vector type: __builtin_nontemporal_* rejects HIP_vector_type.
typedef float f32x4 __attribute__((ext_vector_type(4)));

// v5 (resubmit after infra failure): R4 post-mortem -> pairing doubled
// pinned VGPRs (~128) and cut residency; revert to one point per wave,
// non-persistent (R3 grid). New lever: 8-deep software-pipelined gather
// ring instead of 16-wide prefetch. Same memory-level parallelism per
// wave at ~half the pinned registers -> target <=64 VGPR so 8 waves/SIMD
// fit (double R3's ~5). __launch_bounds__(256, 8) enforces the budget.
__global__ __launch_bounds__(256, 8) void pcf_kernel(
    const float* __restrict__ feat,   // [B,N,C]
    const int*   __restrict__ inds,   // [B,M,K]
    const float* __restrict__ guid,   // [B,M,K,H]
    const float* __restrict__ wnet,   // [B,M,K,CMID]
    float*       __restrict__ out)    // [B,M,C*CMID]
{
    const int wib  = threadIdx.x >> 6;                       // wave-in-block 0..3
    const int wid  = blockIdx.x * 4 + wib;
    const int lane = threadIdx.x & 63;
    if (wid >= TOTAL) return;

    const int b = wid / MM;
    const int h = lane >> 3;  // head for this channel

    const float*  fbase = feat + (size_t)b * NN * CC;
    const int*    idxp  = inds + (size_t)wid * KK;
    const float*  gd    = guid + (size_t)wid * KK * HH;
    const f32x4*  wn4   = (const f32x4*)(wnet + (size_t)wid * KK * CMID);

    // Per-wave wnet tile staged in LDS (1 KiB, one f32x4 per lane, no barrier).
    __shared__ f32x4 swn[4][KK * 4];
    swn[wib][lane] = __builtin_nontemporal_load(&wn4[lane]);

    // Neighbor indices: one 64 B broadcast txn; lane i holds idx[i&15].
    int myidx = idxp[lane & (KK - 1)];

    // Guidance: all 16 independent scalar loads issued up front (16 VGPR).
    float g[KK];
#pragma unroll
    for (int k = 0; k < KK; ++k)
        g[k] = __builtin_nontemporal_load(&gd[k * HH + h]);

    // Gather ring: first 8 of 16 feature rows in flight (8 VGPR).
    float f[8];
#pragma unroll
    for (int k = 0; k < 8; ++k) {
        const int id = __shfl(myidx, k);
        f[k] = fbase[(size_t)id * CC + lane];
    }

    // Keep-alive: pin the ring + guidance so the allocator cannot sink the
    // loads back into the compute loop (R2: VGPR=44 proved it does).
#pragma unroll
    for (int k = 0; k < 8; ++k)
        asm volatile("" :: "v"(f[k]), "v"(g[k]), "v"(g[k + 8]));

    float acc[CMID];
#pragma unroll
    for (int i = 0; i < CMID; ++i) acc[i] = 0.f;

    // Main loop: consume slot (k&7), immediately refill it with row k+8.
    // The refill has 8 iterations (~250 cy of FMA+LDS issue) to land.
#pragma unroll
    for (int k = 0; k < KK; ++k) {
        const float fg = f[k & 7] * g[k];
        if (k < 8) {
            const int id = __shfl(myidx, k + 8);
            f[k & 7] = fbase[(size_t)id * CC + lane];
        }

        const f32x4 w0 = swn[wib][k * 4 + 0];   // same-address broadcast,
        const f32x4 w1 = swn[wib][k * 4 + 1];   // conflict-free ds_read_b128
        const f32x4 w2 = swn[wib][k * 4 + 2];
        const f32x4 w3 = swn[wib][k * 4 + 3];

        acc[0]  += fg * w0.x;  acc[1]  += fg * w0.y;
        acc[2]  += fg * w0.z;  acc[3]  += fg * w0.w;
        acc[4]  += fg * w1.x;  acc[5]  += fg * w1.y;
        acc[6]  += fg * w1.z;  acc[7]  += fg * w1.w;
        acc[8]  += fg * w2.x;  acc[9]  += fg * w2.y;
        acc[10] += fg * w2.z;  acc[11] += fg * w2.w;
        acc[12] += fg * w3.x;  acc[13] += fg * w3.y;
        acc[14] += fg * w3.z;  acc[15] += fg * w3.w;
    }

    // Store: lane c owns out[wid, c*16 .. c*16+15] -> 4 contiguous float4.
    // Plain cached stores (NT stores inflated WRITE_SIZE 410->590 MB in R2).
    f32x4* o = (f32x4*)(out + (size_t)wid * (CC * CMID) + (size_t)lane * CMID);
    f32x4 o0 = {acc[0],  acc[1],  acc[2],  acc[3]};
    f32x4 o1 = {acc[4],  acc[5],  acc[6],  acc[7]};
    f32x4 o2 = {acc[8],  acc[9],  acc[10], acc[11]};
    f32x4 o3 = {acc[12], acc[13], acc[14], acc[15]};
    o[0] = o0;
    o[1] = o1;
    o[2] = o2;
    o[3] = o3;
}

extern "C" void kernel_launch(void* const* d_in, const int* in_sizes, int n_in,
                              void* d_out, int out_size, void* d_ws, size_t ws_size,
                              hipStream_t stream) {
    const float* feat = (const float*)d_in[0];   // [B,N,C] fp32
    const int*   inds = (const int*)d_in[1];     // [B,M,K] int
    const float* guid = (const float*)d_in[2];   // [B,M,K,H] fp32
    const float* wnet = (const float*)d_in[3];   // [B,M,K,CMID] fp32
    float*       out  = (float*)d_out;           // [B,M,C*CMID] fp32

    const int waves_per_block = 4;               // 256 threads
    const int blocks = (TOTAL + waves_per_block - 1) / waves_per_block;  // 25000

    pcf_kernel<<<blocks, 256, 0, stream>>>(feat, inds, guid, wnet, out);
}